// Round 3
// baseline (131.514 us; speedup 1.0000x reference)
//
#include <hip/hip_runtime.h>

// TriangleAttentionStartingNode — MI355X gfx950. f32 global I/O, bf16 MFMA compute.
//
// grid (qhalf=2, i=256), 256 thr. Per block:
//   P0: LN of all 256 positions of row i -> sZ (bf16, once).
//   per head h:
//     P1: K,V projections (MFMA) -> sK / sVt (LDS); Q,G for this block's 128
//         queries stay in registers (transposed C-layout == permuted-k B-frag).
//     P2: flash attention, S^T trick (softmax keys in register dim; per-lane
//         partial sums, 2 shuffles); no max subtraction (post-LN scores are
//         O(1); exp2 arg clamped at 60); gated normalized O^T re-used as
//         permuted-k B-frag against Wo A-frags -> fp32 out accumulators.
//   epilogue: out = acc + bo, float4 stores.
//
// Wb (d_in[6]) unused: its bias broadcasts along the softmax axis and cancels
// exactly (softmax shift invariance).

typedef unsigned short u16;
typedef unsigned int   u32;
typedef __bf16 bf16x8 __attribute__((ext_vector_type(8)));
typedef float  f32x4  __attribute__((ext_vector_type(4)));

union U8 { bf16x8 b; u32 u[4]; };

__device__ __forceinline__ float bf2f(u32 bits) { return __uint_as_float(bits << 16); }
__device__ __forceinline__ u16 f2bf(float f) {
  u32 u = __float_as_uint(f);
  return (u16)((u + 0x7FFFu + ((u >> 16) & 1u)) >> 16);   // RNE
}
__device__ __forceinline__ u32 pk(float a, float b) {
  return (u32)f2bf(a) | ((u32)f2bf(b) << 16);
}
__device__ __forceinline__ f32x4 mfma16(bf16x8 a, bf16x8 b, f32x4 c) {
  return __builtin_amdgcn_mfma_f32_16x16x32_bf16(a, b, c, 0, 0, 0);
}

#define LDZ 40    // 80 B rows: 16B-aligned uint4 frag reads
#define LDK 36    // 72 B rows: 8B-aligned uint2 frag reads
#define LDV 260   // 520 B rows: 8B-aligned uint2 frag reads

__global__ __launch_bounds__(256) void tri_attn_fused(
    const float* __restrict__ z,  const float* __restrict__ ln_g, const float* __restrict__ ln_b,
    const float* __restrict__ Wq, const float* __restrict__ Wk,   const float* __restrict__ Wv,
    const float* __restrict__ Wg, const float* __restrict__ bg,
    const float* __restrict__ Wo, const float* __restrict__ bo,   float* __restrict__ out)
{
  __shared__ u16 sZ [256][LDZ];   // zn[pos][ch]   bf16
  __shared__ u16 sK [256][LDK];   // K[key][ch]    bf16 (per head)
  __shared__ u16 sVt[32][LDV];    // V^T[ch][key]  bf16 (per head)

  const int qhalf = blockIdx.x;
  const int i     = blockIdx.y;
  const int tid   = threadIdx.x;
  const int wave  = tid >> 6, lane = tid & 63, quad = lane >> 4, col = lane & 15;
  const f32x4 z4  = {0.f, 0.f, 0.f, 0.f};

  // ---------------- phase 0: LayerNorm (one thread per position) ----------------
  {
    const float* zr = z + (((i << 8) + tid) << 5);
    float x[32];
#pragma unroll
    for (int e = 0; e < 8; e++) {
      const float4 v = *(const float4*)(zr + e*4);
      x[4*e] = v.x; x[4*e+1] = v.y; x[4*e+2] = v.z; x[4*e+3] = v.w;
    }
    float mu = 0.f;
#pragma unroll
    for (int c = 0; c < 32; c++) mu += x[c];
    mu *= (1.f / 32.f);
    float s2 = 0.f;
#pragma unroll
    for (int c = 0; c < 32; c++) { float d = x[c] - mu; s2 += d * d; }
    const float rstd = rsqrtf(s2 * (1.f / 32.f) + 1e-5f);
    u32* dst = (u32*)&sZ[tid][0];
#pragma unroll
    for (int e = 0; e < 16; e++) {
      const float za = (x[2*e]   - mu) * rstd * ln_g[2*e]   + ln_b[2*e];
      const float zb = (x[2*e+1] - mu) * rstd * ln_g[2*e+1] + ln_b[2*e+1];
      dst[e] = pk(za, zb);
    }
  }
  __syncthreads();

  f32x4 acc[2][2] = {{z4, z4}, {z4, z4}};   // fp32 out accumulators (across heads)
  U8    QB[2];                              // Q permuted-k B-frags (per q-tile)
  float G[2][8];                            // gates, O^T C-layout

  for (int h = 0; h < 4; ++h) {
    // weight fragments (f32 -> bf16 pack), loaded once per head (L1/L2-hot)
    auto ldw = [&](const float* W, int cb) -> U8 {
      const float* p = W + h*1024 + (cb*16 + col)*32 + quad*8;
      const float4 a = *(const float4*)(p);
      const float4 b = *(const float4*)(p + 4);
      U8 t;
      t.u[0] = pk(a.x, a.y); t.u[1] = pk(a.z, a.w);
      t.u[2] = pk(b.x, b.y); t.u[3] = pk(b.z, b.w);
      return t;
    };
    const U8 WkF0 = ldw(Wk,0), WkF1 = ldw(Wk,1);
    const U8 WvF0 = ldw(Wv,0), WvF1 = ldw(Wv,1);
    const U8 WqF0 = ldw(Wq,0), WqF1 = ldw(Wq,1);
    const U8 WgF0 = ldw(Wg,0), WgF1 = ldw(Wg,1);
    float bgl[8];
#pragma unroll
    for (int r = 0; r < 4; r++) {
      bgl[r]     = bg[h*32 + quad*4 + r];
      bgl[4 + r] = bg[h*32 + 16 + quad*4 + r];
    }

    // -------------- phase 1: projections --------------
#pragma unroll
    for (int p = 0; p < 4; p++) {
      const int pbase = (p*4 + wave) * 16, row = pbase + col;
      U8 ZA;
      {
        const uint4 v = *(const uint4*)&sZ[row][quad*8];
        ZA.u[0] = v.x; ZA.u[1] = v.y; ZA.u[2] = v.z; ZA.u[3] = v.w;
      }
      // K^T (C-layout: ch=quad*4+reg, pos=col), V (pos=quad*4+reg, ch=col)
      const f32x4 k0 = mfma16(WkF0.b, ZA.b, z4);
      const f32x4 k1 = mfma16(WkF1.b, ZA.b, z4);
      const f32x4 v0 = mfma16(ZA.b, WvF0.b, z4);
      const f32x4 v1 = mfma16(ZA.b, WvF1.b, z4);
      *(uint2*)&sK[row][quad*4]               = make_uint2(pk(k0[0],k0[1]), pk(k0[2],k0[3]));
      *(uint2*)&sK[row][16 + quad*4]          = make_uint2(pk(k1[0],k1[1]), pk(k1[2],k1[3]));
      *(uint2*)&sVt[col][pbase + quad*4]      = make_uint2(pk(v0[0],v0[1]), pk(v0[2],v0[3]));
      *(uint2*)&sVt[16 + col][pbase + quad*4] = make_uint2(pk(v1[0],v1[1]), pk(v1[2],v1[3]));
      if ((p >> 1) == qhalf) {                // this q-tile belongs to our half
        const int p2 = p & 1;
        const f32x4 q0 = mfma16(WqF0.b, ZA.b, z4);
        const f32x4 q1 = mfma16(WqF1.b, ZA.b, z4);
        const f32x4 g0 = mfma16(WgF0.b, ZA.b, z4);
        const f32x4 g1 = mfma16(WgF1.b, ZA.b, z4);
        QB[p2].u[0] = pk(q0[0],q0[1]); QB[p2].u[1] = pk(q0[2],q0[3]);
        QB[p2].u[2] = pk(q1[0],q1[1]); QB[p2].u[3] = pk(q1[2],q1[3]);
#pragma unroll
        for (int r = 0; r < 4; r++) {
          G[p2][r]     = 1.f / (1.f + __expf(-(g0[r] + bgl[r])));
          G[p2][4 + r] = 1.f / (1.f + __expf(-(g1[r] + bgl[4 + r])));
        }
      }
    }
    __syncthreads();

    // -------------- phase 2: attention + fused out-projection --------------
    const float k2e = 0.17677669529663687f * 1.44269504089f;   // (1/sqrt32)*log2(e)
#pragma unroll
    for (int p2 = 0; p2 < 2; p2++) {
      float l = 0.f;
      f32x4 O0 = z4, O1 = z4;                 // O^T: ch=quad*4+r (+16), q=col
#pragma unroll
      for (int kb = 0; kb < 256; kb += 32) {
        U8 KF0, KF1;
        {
          const uint2 a = *(const uint2*)&sK[kb + col][quad*4];
          const uint2 b = *(const uint2*)&sK[kb + col][16 + quad*4];
          KF0.u[0] = a.x; KF0.u[1] = a.y; KF0.u[2] = b.x; KF0.u[3] = b.y;
          const uint2 c = *(const uint2*)&sK[kb + 16 + col][quad*4];
          const uint2 d = *(const uint2*)&sK[kb + 16 + col][16 + quad*4];
          KF1.u[0] = c.x; KF1.u[1] = c.y; KF1.u[2] = d.x; KF1.u[3] = d.y;
        }
        const f32x4 S0 = mfma16(KF0.b, QB[p2].b, z4);   // keys kb+quad*4+r
        const f32x4 S1 = mfma16(KF1.b, QB[p2].b, z4);   // keys kb+16+quad*4+r
        float ps[8];
#pragma unroll
        for (int r = 0; r < 4; r++) {
          ps[r]     = exp2f(fminf(S0[r] * k2e, 60.f));
          ps[4 + r] = exp2f(fminf(S1[r] * k2e, 60.f));
        }
#pragma unroll
        for (int j = 0; j < 8; j++) l += ps[j];
        U8 PB;
        PB.u[0] = pk(ps[0], ps[1]); PB.u[1] = pk(ps[2], ps[3]);
        PB.u[2] = pk(ps[4], ps[5]); PB.u[3] = pk(ps[6], ps[7]);
        U8 VF0, VF1;
        {
          const uint2 a = *(const uint2*)&sVt[col][kb + quad*4];
          const uint2 b = *(const uint2*)&sVt[col][kb + 16 + quad*4];
          VF0.u[0] = a.x; VF0.u[1] = a.y; VF0.u[2] = b.x; VF0.u[3] = b.y;
          const uint2 c = *(const uint2*)&sVt[16 + col][kb + quad*4];
          const uint2 d = *(const uint2*)&sVt[16 + col][kb + 16 + quad*4];
          VF1.u[0] = c.x; VF1.u[1] = c.y; VF1.u[2] = d.x; VF1.u[3] = d.y;
        }
        O0 = mfma16(VF0.b, PB.b, O0);
        O1 = mfma16(VF1.b, PB.b, O1);
      }
      // l: reduce over quads (keys spread across reg-dim x quad)
      l += __shfl_xor(l, 16);
      l += __shfl_xor(l, 32);
      const float inv = 1.f / l;
      float og[8];
#pragma unroll
      for (int r = 0; r < 4; r++) {
        og[r]     = O0[r] * inv * G[p2][r];
        og[4 + r] = O1[r] * inv * G[p2][4 + r];
      }
      U8 OB;   // gated O^T as permuted-k B-frag (same permutation as below)
      OB.u[0] = pk(og[0], og[1]); OB.u[1] = pk(og[2], og[3]);
      OB.u[2] = pk(og[4], og[5]); OB.u[3] = pk(og[6], og[7]);
      // Wo A-frags with matching k-permutation (f32 -> bf16 pack)
      U8 WoA0, WoA1;
      {
        const float4 a = *(const float4*)(Wo + col*128 + h*32 + quad*4);
        const float4 b = *(const float4*)(Wo + col*128 + h*32 + 16 + quad*4);
        WoA0.u[0] = pk(a.x,a.y); WoA0.u[1] = pk(a.z,a.w);
        WoA0.u[2] = pk(b.x,b.y); WoA0.u[3] = pk(b.z,b.w);
        const float4 c = *(const float4*)(Wo + (16 + col)*128 + h*32 + quad*4);
        const float4 d = *(const float4*)(Wo + (16 + col)*128 + h*32 + 16 + quad*4);
        WoA1.u[0] = pk(c.x,c.y); WoA1.u[1] = pk(c.z,c.w);
        WoA1.u[2] = pk(d.x,d.y); WoA1.u[3] = pk(d.z,d.w);
      }
      acc[p2][0] = mfma16(WoA0.b, OB.b, acc[p2][0]);   // couts 0..15
      acc[p2][1] = mfma16(WoA1.b, OB.b, acc[p2][1]);   // couts 16..31
    }
    __syncthreads();   // protect sK/sVt before next head overwrites
  }

  // ---------------- epilogue: + bo, float4 stores ----------------
  float bo0[4], bo1[4];
#pragma unroll
  for (int r = 0; r < 4; r++) {
    bo0[r] = bo[quad*4 + r];
    bo1[r] = bo[16 + quad*4 + r];
  }
#pragma unroll
  for (int p2 = 0; p2 < 2; p2++) {
    const int pos = (i << 8) + qhalf*128 + (p2*4 + wave)*16 + col;
    float* op = out + pos*32;
    *(float4*)(op + quad*4)      = make_float4(acc[p2][0][0] + bo0[0], acc[p2][0][1] + bo0[1],
                                               acc[p2][0][2] + bo0[2], acc[p2][0][3] + bo0[3]);
    *(float4*)(op + 16 + quad*4) = make_float4(acc[p2][1][0] + bo1[0], acc[p2][1][1] + bo1[1],
                                               acc[p2][1][2] + bo1[2], acc[p2][1][3] + bo1[3]);
  }
}

extern "C" void kernel_launch(void* const* d_in, const int* in_sizes, int n_in,
                              void* d_out, int out_size, void* d_ws, size_t ws_size,
                              hipStream_t stream)
{
  const float* z    = (const float*)d_in[0];
  const float* ln_g = (const float*)d_in[1];
  const float* ln_b = (const float*)d_in[2];
  const float* Wq   = (const float*)d_in[3];
  const float* Wk   = (const float*)d_in[4];
  const float* Wv   = (const float*)d_in[5];
  // d_in[6] = Wb: softmax shift invariance -> exactly cancels, unused.
  const float* Wg   = (const float*)d_in[7];
  const float* bg   = (const float*)d_in[8];
  const float* Wo   = (const float*)d_in[9];
  const float* bo   = (const float*)d_in[10];

  tri_attn_fused<<<dim3(2, 256), 256, 0, stream>>>(z, ln_g, ln_b, Wq, Wk, Wv, Wg, bg, Wo, bo,
                                                   (float*)d_out);
}

// Round 4
// 123.555 us; speedup vs baseline: 1.0644x; 1.0644x over previous
//
#include <hip/hip_runtime.h>

// TriangleAttentionStartingNode — MI355X gfx950. f32 global I/O, bf16 MFMA compute.
//
// R4: VALU-cut round. (a) all f32->bf16 packing via v_perm round-half-up
// (3 ops/pair vs ~9); (b) softmax scale*log2e folded into Q fragment pack
// (deletes 512 per-score muls/thread); (c) exp clamp dropped (post-LN scores
// O(1), no overflow path); (d) tree-reduced l.
//
// Structure (unchanged from R3, which passed at absmax 3.9e-3):
// grid (qhalf=2, i=256), 256 thr. P0: LN -> sZ. Per head: P1 K,V proj -> LDS,
// Q,G in regs (transposed C-layout == permuted-k B-frag); P2 flash attention
// with S^T trick (softmax keys in register dim), gated O^T re-used as
// permuted-k B-frag vs Wo A-frags -> fp32 out accumulators. Wb unused
// (softmax shift invariance).

typedef unsigned short u16;
typedef unsigned int   u32;
typedef __bf16 bf16x8 __attribute__((ext_vector_type(8)));
typedef float  f32x4  __attribute__((ext_vector_type(4)));

union U8 { bf16x8 b; u32 u[4]; };

// round-half-up f32->bf16 pair pack: 2 adds + 1 v_perm
__device__ __forceinline__ u32 pk(float a, float b) {
  const u32 au = __float_as_uint(a) + 0x8000u;
  const u32 bu = __float_as_uint(b) + 0x8000u;
  return __builtin_amdgcn_perm(bu, au, 0x07060302u);  // {b.hi16, a.hi16}
}
__device__ __forceinline__ f32x4 mfma16(bf16x8 a, bf16x8 b, f32x4 c) {
  return __builtin_amdgcn_mfma_f32_16x16x32_bf16(a, b, c, 0, 0, 0);
}

#define LDZ 40    // 80 B rows
#define LDK 36    // 72 B rows
#define LDV 260   // 520 B rows

__global__ __launch_bounds__(256) void tri_attn_fused(
    const float* __restrict__ z,  const float* __restrict__ ln_g, const float* __restrict__ ln_b,
    const float* __restrict__ Wq, const float* __restrict__ Wk,   const float* __restrict__ Wv,
    const float* __restrict__ Wg, const float* __restrict__ bg,
    const float* __restrict__ Wo, const float* __restrict__ bo,   float* __restrict__ out)
{
  __shared__ u16 sZ [256][LDZ];   // zn[pos][ch]   bf16
  __shared__ u16 sK [256][LDK];   // K[key][ch]    bf16 (per head)
  __shared__ u16 sVt[32][LDV];    // V^T[ch][key]  bf16 (per head)

  const int qhalf = blockIdx.x;
  const int i     = blockIdx.y;
  const int tid   = threadIdx.x;
  const int wave  = tid >> 6, lane = tid & 63, quad = lane >> 4, col = lane & 15;
  const f32x4 z4  = {0.f, 0.f, 0.f, 0.f};

  // ---------------- phase 0: LayerNorm (one thread per position) ----------------
  {
    const float* zr = z + (((i << 8) + tid) << 5);
    float x[32];
#pragma unroll
    for (int e = 0; e < 8; e++) {
      const float4 v = *(const float4*)(zr + e*4);
      x[4*e] = v.x; x[4*e+1] = v.y; x[4*e+2] = v.z; x[4*e+3] = v.w;
    }
    float mu = 0.f;
#pragma unroll
    for (int c = 0; c < 32; c++) mu += x[c];
    mu *= (1.f / 32.f);
    float s2 = 0.f;
#pragma unroll
    for (int c = 0; c < 32; c++) { float d = x[c] - mu; s2 += d * d; }
    const float rstd = rsqrtf(s2 * (1.f / 32.f) + 1e-5f);
    u32* dst = (u32*)&sZ[tid][0];
#pragma unroll
    for (int e = 0; e < 16; e++) {
      const float za = (x[2*e]   - mu) * rstd * ln_g[2*e]   + ln_b[2*e];
      const float zb = (x[2*e+1] - mu) * rstd * ln_g[2*e+1] + ln_b[2*e+1];
      dst[e] = pk(za, zb);
    }
  }
  __syncthreads();

  f32x4 acc[2][2] = {{z4, z4}, {z4, z4}};   // fp32 out accumulators (across heads)
  U8    QB[2];                              // Q (pre-scaled) permuted-k B-frags
  float G[2][8];                            // gates, O^T C-layout

  const float k2e = 0.17677669529663687f * 1.44269504089f;   // (1/sqrt32)*log2(e)

  for (int h = 0; h < 4; ++h) {
    // weight fragments (f32 -> bf16 pack), loaded once per head (L1/L2-hot)
    auto ldw = [&](const float* W, int cb) -> U8 {
      const float* p = W + h*1024 + (cb*16 + col)*32 + quad*8;
      const float4 a = *(const float4*)(p);
      const float4 b = *(const float4*)(p + 4);
      U8 t;
      t.u[0] = pk(a.x, a.y); t.u[1] = pk(a.z, a.w);
      t.u[2] = pk(b.x, b.y); t.u[3] = pk(b.z, b.w);
      return t;
    };
    const U8 WkF0 = ldw(Wk,0), WkF1 = ldw(Wk,1);
    const U8 WvF0 = ldw(Wv,0), WvF1 = ldw(Wv,1);
    const U8 WqF0 = ldw(Wq,0), WqF1 = ldw(Wq,1);
    const U8 WgF0 = ldw(Wg,0), WgF1 = ldw(Wg,1);
    float bgl[8];
#pragma unroll
    for (int r = 0; r < 4; r++) {
      bgl[r]     = bg[h*32 + quad*4 + r];
      bgl[4 + r] = bg[h*32 + 16 + quad*4 + r];
    }

    // -------------- phase 1: projections --------------
#pragma unroll
    for (int p = 0; p < 4; p++) {
      const int pbase = (p*4 + wave) * 16, row = pbase + col;
      U8 ZA;
      {
        const uint4 v = *(const uint4*)&sZ[row][quad*8];
        ZA.u[0] = v.x; ZA.u[1] = v.y; ZA.u[2] = v.z; ZA.u[3] = v.w;
      }
      // K^T (C-layout: ch=quad*4+reg, pos=col), V (pos=quad*4+reg, ch=col)
      const f32x4 k0 = mfma16(WkF0.b, ZA.b, z4);
      const f32x4 k1 = mfma16(WkF1.b, ZA.b, z4);
      const f32x4 v0 = mfma16(ZA.b, WvF0.b, z4);
      const f32x4 v1 = mfma16(ZA.b, WvF1.b, z4);
      *(uint2*)&sK[row][quad*4]               = make_uint2(pk(k0[0],k0[1]), pk(k0[2],k0[3]));
      *(uint2*)&sK[row][16 + quad*4]          = make_uint2(pk(k1[0],k1[1]), pk(k1[2],k1[3]));
      *(uint2*)&sVt[col][pbase + quad*4]      = make_uint2(pk(v0[0],v0[1]), pk(v0[2],v0[3]));
      *(uint2*)&sVt[16 + col][pbase + quad*4] = make_uint2(pk(v1[0],v1[1]), pk(v1[2],v1[3]));
      if ((p >> 1) == qhalf) {                // this q-tile belongs to our half
        const int p2 = p & 1;
        const f32x4 q0 = mfma16(WqF0.b, ZA.b, z4);
        const f32x4 q1 = mfma16(WqF1.b, ZA.b, z4);
        const f32x4 g0 = mfma16(WgF0.b, ZA.b, z4);
        const f32x4 g1 = mfma16(WgF1.b, ZA.b, z4);
        // scale folded into Q: S-MFMA then directly feeds exp2
        QB[p2].u[0] = pk(q0[0]*k2e, q0[1]*k2e); QB[p2].u[1] = pk(q0[2]*k2e, q0[3]*k2e);
        QB[p2].u[2] = pk(q1[0]*k2e, q1[1]*k2e); QB[p2].u[3] = pk(q1[2]*k2e, q1[3]*k2e);
#pragma unroll
        for (int r = 0; r < 4; r++) {
          G[p2][r]     = 1.f / (1.f + __expf(-(g0[r] + bgl[r])));
          G[p2][4 + r] = 1.f / (1.f + __expf(-(g1[r] + bgl[4 + r])));
        }
      }
    }
    __syncthreads();

    // -------------- phase 2: attention + fused out-projection --------------
#pragma unroll
    for (int p2 = 0; p2 < 2; p2++) {
      float l = 0.f;
      f32x4 O0 = z4, O1 = z4;                 // O^T: ch=quad*4+r (+16), q=col
#pragma unroll
      for (int kb = 0; kb < 256; kb += 32) {
        U8 KF0, KF1;
        {
          const uint2 a = *(const uint2*)&sK[kb + col][quad*4];
          const uint2 b = *(const uint2*)&sK[kb + col][16 + quad*4];
          KF0.u[0] = a.x; KF0.u[1] = a.y; KF0.u[2] = b.x; KF0.u[3] = b.y;
          const uint2 c = *(const uint2*)&sK[kb + 16 + col][quad*4];
          const uint2 d = *(const uint2*)&sK[kb + 16 + col][16 + quad*4];
          KF1.u[0] = c.x; KF1.u[1] = c.y; KF1.u[2] = d.x; KF1.u[3] = d.y;
        }
        const f32x4 S0 = mfma16(KF0.b, QB[p2].b, z4);   // keys kb+quad*4+r
        const f32x4 S1 = mfma16(KF1.b, QB[p2].b, z4);   // keys kb+16+quad*4+r
        float ps[8];
#pragma unroll
        for (int r = 0; r < 4; r++) {
          ps[r]     = exp2f(S0[r]);     // scale pre-folded into Q; no clamp needed
          ps[4 + r] = exp2f(S1[r]);
        }
        l += ((ps[0] + ps[1]) + (ps[2] + ps[3])) + ((ps[4] + ps[5]) + (ps[6] + ps[7]));
        U8 PB;
        PB.u[0] = pk(ps[0], ps[1]); PB.u[1] = pk(ps[2], ps[3]);
        PB.u[2] = pk(ps[4], ps[5]); PB.u[3] = pk(ps[6], ps[7]);
        U8 VF0, VF1;
        {
          const uint2 a = *(const uint2*)&sVt[col][kb + quad*4];
          const uint2 b = *(const uint2*)&sVt[col][kb + 16 + quad*4];
          VF0.u[0] = a.x; VF0.u[1] = a.y; VF0.u[2] = b.x; VF0.u[3] = b.y;
          const uint2 c = *(const uint2*)&sVt[16 + col][kb + quad*4];
          const uint2 d = *(const uint2*)&sVt[16 + col][kb + 16 + quad*4];
          VF1.u[0] = c.x; VF1.u[1] = c.y; VF1.u[2] = d.x; VF1.u[3] = d.y;
        }
        O0 = mfma16(VF0.b, PB.b, O0);
        O1 = mfma16(VF1.b, PB.b, O1);
      }
      // l: reduce over quads (keys spread across reg-dim x quad)
      l += __shfl_xor(l, 16);
      l += __shfl_xor(l, 32);
      const float inv = 1.f / l;
      float og[8];
#pragma unroll
      for (int r = 0; r < 4; r++) {
        og[r]     = O0[r] * inv * G[p2][r];
        og[4 + r] = O1[r] * inv * G[p2][4 + r];
      }
      U8 OB;   // gated O^T as permuted-k B-frag (same permutation as below)
      OB.u[0] = pk(og[0], og[1]); OB.u[1] = pk(og[2], og[3]);
      OB.u[2] = pk(og[4], og[5]); OB.u[3] = pk(og[6], og[7]);
      // Wo A-frags with matching k-permutation (f32 -> bf16 pack)
      U8 WoA0, WoA1;
      {
        const float4 a = *(const float4*)(Wo + col*128 + h*32 + quad*4);
        const float4 b = *(const float4*)(Wo + col*128 + h*32 + 16 + quad*4);
        WoA0.u[0] = pk(a.x,a.y); WoA0.u[1] = pk(a.z,a.w);
        WoA0.u[2] = pk(b.x,b.y); WoA0.u[3] = pk(b.z,b.w);
        const float4 c = *(const float4*)(Wo + (16 + col)*128 + h*32 + quad*4);
        const float4 d = *(const float4*)(Wo + (16 + col)*128 + h*32 + 16 + quad*4);
        WoA1.u[0] = pk(c.x,c.y); WoA1.u[1] = pk(c.z,c.w);
        WoA1.u[2] = pk(d.x,d.y); WoA1.u[3] = pk(d.z,d.w);
      }
      acc[p2][0] = mfma16(WoA0.b, OB.b, acc[p2][0]);   // couts 0..15
      acc[p2][1] = mfma16(WoA1.b, OB.b, acc[p2][1]);   // couts 16..31
    }
    __syncthreads();   // protect sK/sVt before next head overwrites
  }

  // ---------------- epilogue: + bo, float4 stores ----------------
  float bo0[4], bo1[4];
#pragma unroll
  for (int r = 0; r < 4; r++) {
    bo0[r] = bo[quad*4 + r];
    bo1[r] = bo[16 + quad*4 + r];
  }
#pragma unroll
  for (int p2 = 0; p2 < 2; p2++) {
    const int pos = (i << 8) + qhalf*128 + (p2*4 + wave)*16 + col;
    float* op = out + pos*32;
    *(float4*)(op + quad*4)      = make_float4(acc[p2][0][0] + bo0[0], acc[p2][0][1] + bo0[1],
                                               acc[p2][0][2] + bo0[2], acc[p2][0][3] + bo0[3]);
    *(float4*)(op + 16 + quad*4) = make_float4(acc[p2][1][0] + bo1[0], acc[p2][1][1] + bo1[1],
                                               acc[p2][1][2] + bo1[2], acc[p2][1][3] + bo1[3]);
  }
}

extern "C" void kernel_launch(void* const* d_in, const int* in_sizes, int n_in,
                              void* d_out, int out_size, void* d_ws, size_t ws_size,
                              hipStream_t stream)
{
  const float* z    = (const float*)d_in[0];
  const float* ln_g = (const float*)d_in[1];
  const float* ln_b = (const float*)d_in[2];
  const float* Wq   = (const float*)d_in[3];
  const float* Wk   = (const float*)d_in[4];
  const float* Wv   = (const float*)d_in[5];
  // d_in[6] = Wb: softmax shift invariance -> exactly cancels, unused.
  const float* Wg   = (const float*)d_in[7];
  const float* bg   = (const float*)d_in[8];
  const float* Wo   = (const float*)d_in[9];
  const float* bo   = (const float*)d_in[10];

  tri_attn_fused<<<dim3(2, 256), 256, 0, stream>>>(z, ln_g, ln_b, Wq, Wk, Wv, Wg, bg, Wo, bo,
                                                   (float*)d_out);
}